// Round 8
// baseline (505.136 us; speedup 1.0000x reference)
//
#include <hip/hip_runtime.h>

#define NSEQ 4096
#define BATCH 2
#define ROWS (BATCH * NSEQ)   // 8192
#define NH 8
#define DHD 32

typedef __attribute__((ext_vector_type(8))) short bf16x8;
typedef __attribute__((ext_vector_type(4))) float f32x4;

static __device__ __forceinline__ ushort f2bf(float f) {
    union { float f; uint u; } v; v.f = f;
    uint u = v.u;
    uint r = (u + 0x7fffu + ((u >> 16) & 1u)) >> 16;   // RTNE
    return (ushort)r;
}

// ---------------- prep: x fp32 -> bf16 ----------------
__global__ __launch_bounds__(256) void k_convert_x(const float* __restrict__ x,
                                                   ushort* __restrict__ xb) {
    int i = (blockIdx.x * 256 + threadIdx.x) * 4;   // total 2097152 elems
    float4 v = *(const float4*)(x + i);
    ushort4 o;
    o.x = f2bf(v.x); o.y = f2bf(v.y); o.z = f2bf(v.z); o.w = f2bf(v.w);
    *(ushort4*)(xb + i) = o;
}

// ---------------- prep: W [K=256][ncols] fp32 -> Wt [ncols][256] bf16 ----------------
__global__ __launch_bounds__(256) void k_transpose_w(const float* __restrict__ w,
                                                     ushort* __restrict__ wt, int ncols) {
    int n = blockIdx.x * 256 + threadIdx.x;
    int k = blockIdx.y;   // 0..255
    wt[n * 256 + k] = f2bf(w[k * ncols + n]);
}

// ---------------- QKV GEMM: [8192x256]bf16 @ Wt[768][256] + bias ----------------
// writes: qk [8192][512] (cols 0..255 = Q*(1/16), 256..511 = K),
//         vT [16][32][4096] with columns PERMUTED within each 64-block by
//         sigma^-1(s) = bits {s5,s3,s2,s4,s1,s0} so PV A-fragments come
//         directly from the S^T register layout (no LDS P round-trip).
__global__ __launch_bounds__(256) void k_qkv(const ushort* __restrict__ xb,
                                             const ushort* __restrict__ wt,
                                             const float* __restrict__ bias,
                                             ushort* __restrict__ qk,
                                             ushort* __restrict__ vT) {
    int w = threadIdx.x >> 6, lane = threadIdx.x & 63;
    int lhi = lane >> 4, llo = lane & 15;
    int row0 = blockIdx.x * 64 + w * 16;
    int n0 = blockIdx.y * 64;

    f32x4 acc[4] = {};
#pragma unroll
    for (int ks = 0; ks < 8; ++ks) {
        int k0 = ks * 32 + lhi * 8;
        bf16x8 a = *(const bf16x8*)(xb + (row0 + llo) * 256 + k0);
#pragma unroll
        for (int fn = 0; fn < 4; ++fn) {
            bf16x8 b = *(const bf16x8*)(wt + (n0 + fn * 16 + llo) * 256 + k0);
            acc[fn] = __builtin_amdgcn_mfma_f32_16x16x32_bf16(a, b, acc[fn], 0, 0, 0);
        }
    }
#pragma unroll
    for (int fn = 0; fn < 4; ++fn) {
        int cg = n0 + fn * 16 + llo;
        int three = cg >> 8, rem = cg & 255;
        float bv = bias[cg];
#pragma unroll
        for (int r = 0; r < 4; ++r) {
            int row = row0 + lhi * 4 + r;
            float v = acc[fn][r] + bv;
            if (three == 0) {
                qk[row * 512 + rem] = f2bf(v * 0.0625f);   // pre-scale Q by C^-0.5 = 1/16
            } else if (three == 1) {
                qk[row * 512 + 256 + rem] = f2bf(v);
            } else {
                int bb = row >> 12, n = row & 4095;
                int hh = rem >> 5, dh = rem & 31;
                int s = n & 63;
                int np = (n & ~63) | ((s >> 5) << 5) | (((s & 15) >> 2) << 3)
                       | (((s >> 4) & 1) << 2) | (s & 3);
                vT[((size_t)(bb * NH + hh) * DHD + dh) * NSEQ + np] = f2bf(v);
            }
        }
    }
}

// ---------------- flash attention, d-split x2: 1 wave = 16 q-rows x 4096 keys x 16 dims ----------------
// Two independent waves (dh=0/1) cover a q-tile: each computes the full softmax
// (duplicated, cheap) and one 16-wide d-half of PV; writes its own 16 cols.
// No cross-wave coupling, no LDS. 8192 waves -> target 8 waves/SIMD via
// NATURAL register allocation (no forced launch_bounds cap -> no spill).
__global__ __launch_bounds__(256) void k_attn(const ushort* __restrict__ qk,
                                              const ushort* __restrict__ vT,
                                              ushort* __restrict__ attn_out) {
    int w = threadIdx.x >> 6, lane = threadIdx.x & 63;
    int lhi = lane >> 4, llo = lane & 15;
    // XCD swizzle: 2048 blocks; each XCD gets 256 contiguous blocks = 2 bh
    // slices (K+V ~1 MB, L2-resident).
    int bidswz = (blockIdx.x & 7) * 256 + (blockIdx.x >> 3);
    int wid = bidswz * 4 + w;              // 0..8191 (bijective)
    int tile = wid >> 1;                   // 0..4095
    int dh = wid & 1;                      // d-half: 0 -> cols 0..15, 1 -> 16..31
    int bh = tile >> 8;                    // 0..15 (b*8+h)
    int qt = tile & 255;
    int b = bh >> 3, h = bh & 7;
    int q0 = qt * 16;

    const ushort* qbase = qk + (size_t)(b * NSEQ) * 512 + h * DHD;
    const ushort* kbase = qbase + 256;
    const ushort* vbase = vT + (size_t)bh * DHD * NSEQ;
    const ushort* pv = vbase + (llo + 16 * dh) * NSEQ + lhi * 8;
    const ushort* pk0 = kbase + llo * 512 + lhi * 8;

    bf16x8 qf = *(const bf16x8*)(qbase + (q0 + llo) * 512 + lhi * 8);
    // constant ones-column B fragment: col llo==0 gets 1.0 for all k
    short onebits = (llo == 0) ? (short)0x3F80 : (short)0;
    bf16x8 va2 = {onebits, onebits, onebits, onebits, onebits, onebits, onebits, onebits};

    f32x4 acc0 = {}, acc2 = {};
    const float L2E = 1.4426950408889634f;
    float mrun = 0.f;      // deferred running max for q-row llo
    float nmL2E = 0.f;     // -mrun * L2E
    float mthr = 8.f;      // mrun + THR
    const f32x4 zf = {0.f, 0.f, 0.f, 0.f};

#pragma unroll 1
    for (int kv = 0; kv < NSEQ; kv += 64) {
        // ---- loads (K first: S-MFMA waits only on K; V completes under softmax)
        bf16x8 k0 = *(const bf16x8*)(pk0 + (kv) * 512);
        bf16x8 k1 = *(const bf16x8*)(pk0 + (kv + 16) * 512);
        bf16x8 k2 = *(const bf16x8*)(pk0 + (kv + 32) * 512);
        bf16x8 k3 = *(const bf16x8*)(pk0 + (kv + 48) * 512);
        bf16x8 v0 = *(const bf16x8*)(pv + kv);
        bf16x8 v1 = *(const bf16x8*)(pv + kv + 32);
        // ---- S^T: lane holds S[q=llo][key = kv + st*16 + lhi*4 + r]
        f32x4 sf0 = __builtin_amdgcn_mfma_f32_16x16x32_bf16(k0, qf, zf, 0, 0, 0);
        f32x4 sf1 = __builtin_amdgcn_mfma_f32_16x16x32_bf16(k1, qf, zf, 0, 0, 0);
        f32x4 sf2 = __builtin_amdgcn_mfma_f32_16x16x32_bf16(k2, qf, zf, 0, 0, 0);
        f32x4 sf3 = __builtin_amdgcn_mfma_f32_16x16x32_bf16(k3, qf, zf, 0, 0, 0);
        // ---- per-lane partial max; deferred-max check (no shuffles fast path)
        float t0 = fmaxf(fmaxf(sf0[0], sf0[1]), fmaxf(sf0[2], sf0[3]));
        float t1 = fmaxf(fmaxf(sf1[0], sf1[1]), fmaxf(sf1[2], sf1[3]));
        float t2 = fmaxf(fmaxf(sf2[0], sf2[1]), fmaxf(sf2[2], sf2[3]));
        float t3 = fmaxf(fmaxf(sf3[0], sf3[1]), fmaxf(sf3[2], sf3[3]));
        float tm = fmaxf(fmaxf(t0, t1), fmaxf(t2, t3));
        if (!__all(tm <= mthr)) {
            // slow path (rare; deterministic, identical across the dh pair)
            float rmax = fmaxf(tm, __shfl_xor(tm, 16));
            rmax = fmaxf(rmax, __shfl_xor(rmax, 32));
            float mnew = fmaxf(mrun, rmax);
            float corr = __builtin_amdgcn_exp2f((mrun - mnew) * L2E);
            mrun = mnew; nmL2E = -mrun * L2E; mthr = mrun + 8.f;
#pragma unroll
            for (int r = 0; r < 4; ++r) {
                float fc = __shfl(corr, lhi * 4 + r);
                acc0[r] *= fc; acc2[r] *= fc;
            }
        }
        // ---- P = exp2(S*L2E - m*L2E); pack via v_cvt_pk_bf16_f32
        float e00 = __builtin_amdgcn_exp2f(__builtin_fmaf(sf0[0], L2E, nmL2E));
        float e01 = __builtin_amdgcn_exp2f(__builtin_fmaf(sf0[1], L2E, nmL2E));
        float e02 = __builtin_amdgcn_exp2f(__builtin_fmaf(sf0[2], L2E, nmL2E));
        float e03 = __builtin_amdgcn_exp2f(__builtin_fmaf(sf0[3], L2E, nmL2E));
        float e10 = __builtin_amdgcn_exp2f(__builtin_fmaf(sf1[0], L2E, nmL2E));
        float e11 = __builtin_amdgcn_exp2f(__builtin_fmaf(sf1[1], L2E, nmL2E));
        float e12 = __builtin_amdgcn_exp2f(__builtin_fmaf(sf1[2], L2E, nmL2E));
        float e13 = __builtin_amdgcn_exp2f(__builtin_fmaf(sf1[3], L2E, nmL2E));
        float e20 = __builtin_amdgcn_exp2f(__builtin_fmaf(sf2[0], L2E, nmL2E));
        float e21 = __builtin_amdgcn_exp2f(__builtin_fmaf(sf2[1], L2E, nmL2E));
        float e22 = __builtin_amdgcn_exp2f(__builtin_fmaf(sf2[2], L2E, nmL2E));
        float e23 = __builtin_amdgcn_exp2f(__builtin_fmaf(sf2[3], L2E, nmL2E));
        float e30 = __builtin_amdgcn_exp2f(__builtin_fmaf(sf3[0], L2E, nmL2E));
        float e31 = __builtin_amdgcn_exp2f(__builtin_fmaf(sf3[1], L2E, nmL2E));
        float e32 = __builtin_amdgcn_exp2f(__builtin_fmaf(sf3[2], L2E, nmL2E));
        float e33 = __builtin_amdgcn_exp2f(__builtin_fmaf(sf3[3], L2E, nmL2E));
        union PU { uint u[4]; bf16x8 v; };
        PU pa0, pa1;
        asm("v_cvt_pk_bf16_f32 %0, %1, %2" : "=v"(pa0.u[0]) : "v"(e00), "v"(e01));
        asm("v_cvt_pk_bf16_f32 %0, %1, %2" : "=v"(pa0.u[1]) : "v"(e02), "v"(e03));
        asm("v_cvt_pk_bf16_f32 %0, %1, %2" : "=v"(pa0.u[2]) : "v"(e10), "v"(e11));
        asm("v_cvt_pk_bf16_f32 %0, %1, %2" : "=v"(pa0.u[3]) : "v"(e12), "v"(e13));
        asm("v_cvt_pk_bf16_f32 %0, %1, %2" : "=v"(pa1.u[0]) : "v"(e20), "v"(e21));
        asm("v_cvt_pk_bf16_f32 %0, %1, %2" : "=v"(pa1.u[1]) : "v"(e22), "v"(e23));
        asm("v_cvt_pk_bf16_f32 %0, %1, %2" : "=v"(pa1.u[2]) : "v"(e30), "v"(e31));
        asm("v_cvt_pk_bf16_f32 %0, %1, %2" : "=v"(pa1.u[3]) : "v"(e32), "v"(e33));
        // ---- PV (one d-half) + row-sum via ones fragment
        acc0 = __builtin_amdgcn_mfma_f32_16x16x32_bf16(pa0.v, v0, acc0, 0, 0, 0);
        acc2 = __builtin_amdgcn_mfma_f32_16x16x32_bf16(pa0.v, va2, acc2, 0, 0, 0);
        acc0 = __builtin_amdgcn_mfma_f32_16x16x32_bf16(pa1.v, v1, acc0, 0, 0, 0);
        acc2 = __builtin_amdgcn_mfma_f32_16x16x32_bf16(pa1.v, va2, acc2, 0, 0, 0);
    }

    // epilogue: l[q-row lhi*4+r] lives in acc2[r] of lane lhi*16 (col 0);
    // identical in both dh waves -> consistent normalization.
#pragma unroll
    for (int r = 0; r < 4; ++r) {
        float ls = __shfl(acc2[r], lhi * 16);
        float li = 1.f / ls;
        int row = q0 + lhi * 4 + r;
        size_t orow = ((size_t)(b * NSEQ) + row) * 256 + h * DHD;
        attn_out[orow + dh * 16 + llo] = f2bf(acc0[r] * li);
    }
}

// ---------------- proj GEMM: [8192x256]bf16 @ Wt[256][256] + bias -> fp32 ----------------
__global__ __launch_bounds__(256) void k_proj(const ushort* __restrict__ aout,
                                              const ushort* __restrict__ wt,
                                              const float* __restrict__ bias,
                                              float* __restrict__ out) {
    int w = threadIdx.x >> 6, lane = threadIdx.x & 63;
    int lhi = lane >> 4, llo = lane & 15;
    int row0 = blockIdx.x * 64 + w * 16;
    int n0 = blockIdx.y * 64;

    f32x4 acc[4] = {};
#pragma unroll
    for (int ks = 0; ks < 8; ++ks) {
        int k0 = ks * 32 + lhi * 8;
        bf16x8 a = *(const bf16x8*)(aout + (row0 + llo) * 256 + k0);
#pragma unroll
        for (int fn = 0; fn < 4; ++fn) {
            bf16x8 b = *(const bf16x8*)(wt + (n0 + fn * 16 + llo) * 256 + k0);
            acc[fn] = __builtin_amdgcn_mfma_f32_16x16x32_bf16(a, b, acc[fn], 0, 0, 0);
        }
    }
#pragma unroll
    for (int fn = 0; fn < 4; ++fn) {
        int cg = n0 + fn * 16 + llo;
        float bv = bias[cg];
#pragma unroll
        for (int r = 0; r < 4; ++r) {
            int row = row0 + lhi * 4 + r;
            out[(size_t)row * 256 + cg] = acc[fn][r] + bv;
        }
    }
}

extern "C" void kernel_launch(void* const* d_in, const int* in_sizes, int n_in,
                              void* d_out, int out_size, void* d_ws, size_t ws_size,
                              hipStream_t stream) {
    const float* x     = (const float*)d_in[0];
    const float* Wqkv  = (const float*)d_in[1];
    const float* bqkv  = (const float*)d_in[2];
    const float* Wproj = (const float*)d_in[3];
    const float* bproj = (const float*)d_in[4];
    float* out = (float*)d_out;

    char* ws = (char*)d_ws;
    ushort* xb     = (ushort*)(ws);                 // 8192*256*2   = 4,194,304
    ushort* wqkvT  = (ushort*)(ws + 4194304);       // 768*256*2    =   393,216
    ushort* wprojT = (ushort*)(ws + 4587520);       // 256*256*2    =   131,072
    ushort* qkbuf  = (ushort*)(ws + 4718592);       // 8192*512*2   = 8,388,608
    ushort* vT     = (ushort*)(ws + 13107200);      // 16*32*4096*2 = 4,194,304
    ushort* aoutb  = (ushort*)(ws + 17301504);      // 8192*256*2   = 4,194,304
    // total ws use: 21,495,808 bytes (proven-safe layout)

    k_convert_x<<<2048, 256, 0, stream>>>(x, xb);
    k_transpose_w<<<dim3(3, 256), 256, 0, stream>>>(Wqkv, wqkvT, 768);
    k_transpose_w<<<dim3(1, 256), 256, 0, stream>>>(Wproj, wprojT, 256);
    k_qkv<<<dim3(128, 12), 256, 0, stream>>>(xb, wqkvT, bqkv, qkbuf, vT);
    k_attn<<<2048, 256, 0, stream>>>(qkbuf, vT, aoutb);
    k_proj<<<dim3(128, 4), 256, 0, stream>>>(aoutb, wprojT, bproj, out);
}

// Round 9
// 142.208 us; speedup vs baseline: 3.5521x; 3.5521x over previous
//
#include <hip/hip_runtime.h>

#define NSEQ 4096
#define BATCH 2
#define ROWS (BATCH * NSEQ)   // 8192
#define NH 8
#define DHD 32

typedef __attribute__((ext_vector_type(8))) short bf16x8;
typedef __attribute__((ext_vector_type(4))) float f32x4;

static __device__ __forceinline__ ushort f2bf(float f) {
    union { float f; uint u; } v; v.f = f;
    uint u = v.u;
    uint r = (u + 0x7fffu + ((u >> 16) & 1u)) >> 16;   // RTNE
    return (ushort)r;
}

// ---------------- prep: x fp32 -> bf16 ----------------
__global__ __launch_bounds__(256) void k_convert_x(const float* __restrict__ x,
                                                   ushort* __restrict__ xb) {
    int i = (blockIdx.x * 256 + threadIdx.x) * 4;   // total 2097152 elems
    float4 v = *(const float4*)(x + i);
    ushort4 o;
    o.x = f2bf(v.x); o.y = f2bf(v.y); o.z = f2bf(v.z); o.w = f2bf(v.w);
    *(ushort4*)(xb + i) = o;
}

// ---------------- prep: W [K=256][ncols] fp32 -> Wt [ncols][256] bf16 ----------------
__global__ __launch_bounds__(256) void k_transpose_w(const float* __restrict__ w,
                                                     ushort* __restrict__ wt, int ncols) {
    int n = blockIdx.x * 256 + threadIdx.x;
    int k = blockIdx.y;   // 0..255
    wt[n * 256 + k] = f2bf(w[k * ncols + n]);
}

// ---------------- QKV GEMM: [8192x256]bf16 @ Wt[768][256] + bias ----------------
// writes HEAD-MAJOR buffers so attention tiles are CONTIGUOUS in memory:
//   qh[bh][n][32] = Q*(1/16), kh[bh][n][32] = K,
//   vT[bh][dh][4096] with columns permuted within each 64-block by
//   sigma^-1(s) = bits {s5,s3,s2,s4,s1,s0} (register-direct PV path).
__global__ __launch_bounds__(256) void k_qkv(const ushort* __restrict__ xb,
                                             const ushort* __restrict__ wt,
                                             const float* __restrict__ bias,
                                             ushort* __restrict__ qh,
                                             ushort* __restrict__ kh,
                                             ushort* __restrict__ vT) {
    int w = threadIdx.x >> 6, lane = threadIdx.x & 63;
    int lhi = lane >> 4, llo = lane & 15;
    int row0 = blockIdx.x * 64 + w * 16;
    int n0 = blockIdx.y * 64;

    f32x4 acc[4] = {};
#pragma unroll
    for (int ks = 0; ks < 8; ++ks) {
        int k0 = ks * 32 + lhi * 8;
        bf16x8 a = *(const bf16x8*)(xb + (row0 + llo) * 256 + k0);
#pragma unroll
        for (int fn = 0; fn < 4; ++fn) {
            bf16x8 b = *(const bf16x8*)(wt + (n0 + fn * 16 + llo) * 256 + k0);
            acc[fn] = __builtin_amdgcn_mfma_f32_16x16x32_bf16(a, b, acc[fn], 0, 0, 0);
        }
    }
#pragma unroll
    for (int fn = 0; fn < 4; ++fn) {
        int cg = n0 + fn * 16 + llo;
        int three = cg >> 8, rem = cg & 255;
        int hh = rem >> 5, dh = rem & 31;
        float bv = bias[cg];
#pragma unroll
        for (int r = 0; r < 4; ++r) {
            int row = row0 + lhi * 4 + r;
            float v = acc[fn][r] + bv;
            int bb = row >> 12, n = row & 4095;
            size_t hb = (size_t)(bb * NH + hh);
            if (three == 0) {
                qh[(hb * 4096 + n) * 32 + dh] = f2bf(v * 0.0625f);  // Q * C^-0.5
            } else if (three == 1) {
                kh[(hb * 4096 + n) * 32 + dh] = f2bf(v);
            } else {
                int s = n & 63;
                int np = (n & ~63) | ((s >> 5) << 5) | (((s & 15) >> 2) << 3)
                       | (((s >> 4) & 1) << 2) | (s & 3);
                vT[(hb * DHD + dh) * NSEQ + np] = f2bf(v);
            }
        }
    }
}

// ---------------- flash attention: block = 4 waves = 4 q-tiles of ONE head ----------------
// K/V tiles staged in LDS once per block with COALESCED loads (contiguous
// head-major layout), consumed by all 4 waves -> kills the scattered-load
// TCP saturation (~2250 cyc/wave-tile invariant of r1-r8). Double-buffered,
// early-issued stage loads (T14), 2 barriers/tile. Per-wave math = round 5.
__global__ __launch_bounds__(256) void k_attn(const ushort* __restrict__ qh,
                                              const ushort* __restrict__ kh,
                                              const ushort* __restrict__ vT,
                                              ushort* __restrict__ attn_out) {
    __shared__ __align__(16) ushort Klds[2][64][40];   // 64 keys x 32 dh, rows padded to 80B
    __shared__ __align__(16) ushort Vlds[2][32][72];   // 32 dh x 64 keys, rows padded to 144B
    int t = threadIdx.x;
    int w = t >> 6, lane = t & 63;
    int lhi = lane >> 4, llo = lane & 15;
    // XCD swizzle: bid%8 = XCD; give each XCD 2 bh slices (Q+K+V ~1.5MB, L2-fit).
    int xcd = blockIdx.x & 7, qp = blockIdx.x >> 3;    // qp 0..127
    int bh = xcd * 2 + (qp >> 6);
    int qblk = qp & 63;
    int b = bh >> 3, h = bh & 7;
    int q0 = qblk * 64 + w * 16;

    const ushort* qbase = qh + (size_t)bh * 4096 * 32;
    // staging pointers for this thread (coalesced: 256 thr x 16B = full tile)
    const ushort* kg = kh + (size_t)bh * 4096 * 32 + (t >> 2) * 32 + (t & 3) * 8;
    const ushort* vg = vT + (size_t)bh * 32 * 4096 + (t >> 3) * 4096 + (t & 7) * 8;
    ushort* klp = &Klds[0][t >> 2][(t & 3) * 8];
    ushort* vlp = &Vlds[0][t >> 3][(t & 7) * 8];
    const int KLB = 64 * 40, VLB = 32 * 72;            // buffer strides (ushorts)

    bf16x8 qf = *(const bf16x8*)(qbase + (q0 + llo) * 32 + lhi * 8);
    short onebits = (llo == 0) ? (short)0x3F80 : (short)0;
    bf16x8 va2 = {onebits, onebits, onebits, onebits, onebits, onebits, onebits, onebits};

    f32x4 acc0 = {}, acc1 = {}, acc2 = {};
    const float L2E = 1.4426950408889634f;
    float mrun = 0.f, nmL2E = 0.f, mthr = 8.f;
    const f32x4 zf = {0.f, 0.f, 0.f, 0.f};

    // prologue: stage tile 0 into buffer 0
    {
        bf16x8 ks = *(const bf16x8*)kg;
        bf16x8 vs = *(const bf16x8*)vg;
        *(bf16x8*)klp = ks;
        *(bf16x8*)vlp = vs;
    }
    __syncthreads();

    bf16x8 ksr, vsr;
#pragma unroll 1
    for (int ti = 0; ti < 64; ++ti) {
        int cur = ti & 1;
        if (ti + 1 < 64) {   // issue next tile's global loads EARLY (hide under compute)
            ksr = *(const bf16x8*)(kg + (ti + 1) * 2048);
            vsr = *(const bf16x8*)(vg + (ti + 1) * 64);
        }
        const ushort* Kb = &Klds[cur][0][0];
        const ushort* Vb = &Vlds[cur][0][0];
        // ---- fragments from LDS (2-way banks = free)
        bf16x8 k0 = *(const bf16x8*)(Kb + (llo) * 40 + lhi * 8);
        bf16x8 k1 = *(const bf16x8*)(Kb + (16 + llo) * 40 + lhi * 8);
        bf16x8 k2 = *(const bf16x8*)(Kb + (32 + llo) * 40 + lhi * 8);
        bf16x8 k3 = *(const bf16x8*)(Kb + (48 + llo) * 40 + lhi * 8);
        bf16x8 v00 = *(const bf16x8*)(Vb + llo * 72 + lhi * 8);
        bf16x8 v01 = *(const bf16x8*)(Vb + (llo + 16) * 72 + lhi * 8);
        bf16x8 v10 = *(const bf16x8*)(Vb + llo * 72 + 32 + lhi * 8);
        bf16x8 v11 = *(const bf16x8*)(Vb + (llo + 16) * 72 + 32 + lhi * 8);
        // ---- S^T: lane holds S[q=llo][key = ti*64 + st*16 + lhi*4 + r]
        f32x4 sf0 = __builtin_amdgcn_mfma_f32_16x16x32_bf16(k0, qf, zf, 0, 0, 0);
        f32x4 sf1 = __builtin_amdgcn_mfma_f32_16x16x32_bf16(k1, qf, zf, 0, 0, 0);
        f32x4 sf2 = __builtin_amdgcn_mfma_f32_16x16x32_bf16(k2, qf, zf, 0, 0, 0);
        f32x4 sf3 = __builtin_amdgcn_mfma_f32_16x16x32_bf16(k3, qf, zf, 0, 0, 0);
        // ---- deferred-max check (no shuffles in fast path)
        float t0 = fmaxf(fmaxf(sf0[0], sf0[1]), fmaxf(sf0[2], sf0[3]));
        float t1 = fmaxf(fmaxf(sf1[0], sf1[1]), fmaxf(sf1[2], sf1[3]));
        float t2 = fmaxf(fmaxf(sf2[0], sf2[1]), fmaxf(sf2[2], sf2[3]));
        float t3 = fmaxf(fmaxf(sf3[0], sf3[1]), fmaxf(sf3[2], sf3[3]));
        float tm = fmaxf(fmaxf(t0, t1), fmaxf(t2, t3));
        if (!__all(tm <= mthr)) {
            float rmax = fmaxf(tm, __shfl_xor(tm, 16));
            rmax = fmaxf(rmax, __shfl_xor(rmax, 32));
            float mnew = fmaxf(mrun, rmax);
            float corr = __builtin_amdgcn_exp2f((mrun - mnew) * L2E);
            mrun = mnew; nmL2E = -mrun * L2E; mthr = mrun + 8.f;
#pragma unroll
            for (int r = 0; r < 4; ++r) {
                float fc = __shfl(corr, lhi * 4 + r);
                acc0[r] *= fc; acc1[r] *= fc; acc2[r] *= fc;
            }
        }
        // ---- P = exp2(S*L2E - m*L2E); pack via v_cvt_pk_bf16_f32
        float e00 = __builtin_amdgcn_exp2f(__builtin_fmaf(sf0[0], L2E, nmL2E));
        float e01 = __builtin_amdgcn_exp2f(__builtin_fmaf(sf0[1], L2E, nmL2E));
        float e02 = __builtin_amdgcn_exp2f(__builtin_fmaf(sf0[2], L2E, nmL2E));
        float e03 = __builtin_amdgcn_exp2f(__builtin_fmaf(sf0[3], L2E, nmL2E));
        float e10 = __builtin_amdgcn_exp2f(__builtin_fmaf(sf1[0], L2E, nmL2E));
        float e11 = __builtin_amdgcn_exp2f(__builtin_fmaf(sf1[1], L2E, nmL2E));
        float e12 = __builtin_amdgcn_exp2f(__builtin_fmaf(sf1[2], L2E, nmL2E));
        float e13 = __builtin_amdgcn_exp2f(__builtin_fmaf(sf1[3], L2E, nmL2E));
        float e20 = __builtin_amdgcn_exp2f(__builtin_fmaf(sf2[0], L2E, nmL2E));
        float e21 = __builtin_amdgcn_exp2f(__builtin_fmaf(sf2[1], L2E, nmL2E));
        float e22 = __builtin_amdgcn_exp2f(__builtin_fmaf(sf2[2], L2E, nmL2E));
        float e23 = __builtin_amdgcn_exp2f(__builtin_fmaf(sf2[3], L2E, nmL2E));
        float e30 = __builtin_amdgcn_exp2f(__builtin_fmaf(sf3[0], L2E, nmL2E));
        float e31 = __builtin_amdgcn_exp2f(__builtin_fmaf(sf3[1], L2E, nmL2E));
        float e32 = __builtin_amdgcn_exp2f(__builtin_fmaf(sf3[2], L2E, nmL2E));
        float e33 = __builtin_amdgcn_exp2f(__builtin_fmaf(sf3[3], L2E, nmL2E));
        union PU { uint u[4]; bf16x8 v; };
        PU pa0, pa1;
        asm("v_cvt_pk_bf16_f32 %0, %1, %2" : "=v"(pa0.u[0]) : "v"(e00), "v"(e01));
        asm("v_cvt_pk_bf16_f32 %0, %1, %2" : "=v"(pa0.u[1]) : "v"(e02), "v"(e03));
        asm("v_cvt_pk_bf16_f32 %0, %1, %2" : "=v"(pa0.u[2]) : "v"(e10), "v"(e11));
        asm("v_cvt_pk_bf16_f32 %0, %1, %2" : "=v"(pa0.u[3]) : "v"(e12), "v"(e13));
        asm("v_cvt_pk_bf16_f32 %0, %1, %2" : "=v"(pa1.u[0]) : "v"(e20), "v"(e21));
        asm("v_cvt_pk_bf16_f32 %0, %1, %2" : "=v"(pa1.u[1]) : "v"(e22), "v"(e23));
        asm("v_cvt_pk_bf16_f32 %0, %1, %2" : "=v"(pa1.u[2]) : "v"(e30), "v"(e31));
        asm("v_cvt_pk_bf16_f32 %0, %1, %2" : "=v"(pa1.u[3]) : "v"(e32), "v"(e33));
        // ---- PV (sigma-permuted V) + row-sums via ones fragment
        acc0 = __builtin_amdgcn_mfma_f32_16x16x32_bf16(pa0.v, v00, acc0, 0, 0, 0);
        acc1 = __builtin_amdgcn_mfma_f32_16x16x32_bf16(pa0.v, v01, acc1, 0, 0, 0);
        acc2 = __builtin_amdgcn_mfma_f32_16x16x32_bf16(pa0.v, va2, acc2, 0, 0, 0);
        acc0 = __builtin_amdgcn_mfma_f32_16x16x32_bf16(pa1.v, v10, acc0, 0, 0, 0);
        acc1 = __builtin_amdgcn_mfma_f32_16x16x32_bf16(pa1.v, v11, acc1, 0, 0, 0);
        acc2 = __builtin_amdgcn_mfma_f32_16x16x32_bf16(pa1.v, va2, acc2, 0, 0, 0);
        // ---- swap buffers: all waves done reading buf[cur]; write buf[cur^1]
        __syncthreads();
        if (ti + 1 < 64) {
            int nxt = (ti + 1) & 1;
            *(bf16x8*)(klp + nxt * KLB) = ksr;
            *(bf16x8*)(vlp + nxt * VLB) = vsr;
            __syncthreads();
        }
    }

    // epilogue: l[q-row lhi*4+r] lives in acc2[r] of lane lhi*16 (col 0)
#pragma unroll
    for (int r = 0; r < 4; ++r) {
        float ls = __shfl(acc2[r], lhi * 16);
        float li = 1.f / ls;
        int row = q0 + lhi * 4 + r;
        size_t orow = ((size_t)(b * NSEQ) + row) * 256 + h * DHD;
        attn_out[orow + llo] = f2bf(acc0[r] * li);
        attn_out[orow + 16 + llo] = f2bf(acc1[r] * li);
    }
}

// ---------------- proj GEMM: [8192x256]bf16 @ Wt[256][256] + bias -> fp32 ----------------
__global__ __launch_bounds__(256) void k_proj(const ushort* __restrict__ aout,
                                              const ushort* __restrict__ wt,
                                              const float* __restrict__ bias,
                                              float* __restrict__ out) {
    int w = threadIdx.x >> 6, lane = threadIdx.x & 63;
    int lhi = lane >> 4, llo = lane & 15;
    int row0 = blockIdx.x * 64 + w * 16;
    int n0 = blockIdx.y * 64;

    f32x4 acc[4] = {};
#pragma unroll
    for (int ks = 0; ks < 8; ++ks) {
        int k0 = ks * 32 + lhi * 8;
        bf16x8 a = *(const bf16x8*)(aout + (row0 + llo) * 256 + k0);
#pragma unroll
        for (int fn = 0; fn < 4; ++fn) {
            bf16x8 b = *(const bf16x8*)(wt + (n0 + fn * 16 + llo) * 256 + k0);
            acc[fn] = __builtin_amdgcn_mfma_f32_16x16x32_bf16(a, b, acc[fn], 0, 0, 0);
        }
    }
#pragma unroll
    for (int fn = 0; fn < 4; ++fn) {
        int cg = n0 + fn * 16 + llo;
        float bv = bias[cg];
#pragma unroll
        for (int r = 0; r < 4; ++r) {
            int row = row0 + lhi * 4 + r;
            out[(size_t)row * 256 + cg] = acc[fn][r] + bv;
        }
    }
}

extern "C" void kernel_launch(void* const* d_in, const int* in_sizes, int n_in,
                              void* d_out, int out_size, void* d_ws, size_t ws_size,
                              hipStream_t stream) {
    const float* x     = (const float*)d_in[0];
    const float* Wqkv  = (const float*)d_in[1];
    const float* bqkv  = (const float*)d_in[2];
    const float* Wproj = (const float*)d_in[3];
    const float* bproj = (const float*)d_in[4];
    float* out = (float*)d_out;

    char* ws = (char*)d_ws;
    ushort* xb     = (ushort*)(ws);                 // 8192*256*2   = 4,194,304
    ushort* wqkvT  = (ushort*)(ws + 4194304);       // 768*256*2    =   393,216
    ushort* wprojT = (ushort*)(ws + 4587520);       // 256*256*2    =   131,072
    ushort* qhb    = (ushort*)(ws + 4718592);       // 16*4096*32*2 = 4,194,304
    ushort* khb    = (ushort*)(ws + 8912896);       // 16*4096*32*2 = 4,194,304
    ushort* vT     = (ushort*)(ws + 13107200);      // 16*32*4096*2 = 4,194,304
    ushort* aoutb  = (ushort*)(ws + 17301504);      // 8192*256*2   = 4,194,304
    // total ws use: 21,495,808 bytes (proven-safe size)

    k_convert_x<<<2048, 256, 0, stream>>>(x, xb);
    k_transpose_w<<<dim3(3, 256), 256, 0, stream>>>(Wqkv, wqkvT, 768);
    k_transpose_w<<<dim3(1, 256), 256, 0, stream>>>(Wproj, wprojT, 256);
    k_qkv<<<dim3(128, 12), 256, 0, stream>>>(xb, wqkvT, bqkv, qhb, khb, vT);
    k_attn<<<1024, 256, 0, stream>>>(qhb, khb, vT, aoutb);
    k_proj<<<dim3(128, 4), 256, 0, stream>>>(aoutb, wprojT, bproj, out);
}

// Round 10
// 131.244 us; speedup vs baseline: 3.8488x; 1.0835x over previous
//
#include <hip/hip_runtime.h>

#define NSEQ 4096
#define BATCH 2
#define ROWS (BATCH * NSEQ)   // 8192
#define NH 8
#define DHD 32

typedef __attribute__((ext_vector_type(8))) short bf16x8;
typedef __attribute__((ext_vector_type(4))) float f32x4;

static __device__ __forceinline__ ushort f2bf(float f) {
    union { float f; uint u; } v; v.f = f;
    uint u = v.u;
    uint r = (u + 0x7fffu + ((u >> 16) & 1u)) >> 16;   // RTNE
    return (ushort)r;
}

// ---------------- prep: x fp32 -> bf16 ----------------
__global__ __launch_bounds__(256) void k_convert_x(const float* __restrict__ x,
                                                   ushort* __restrict__ xb) {
    int i = (blockIdx.x * 256 + threadIdx.x) * 4;   // total 2097152 elems
    float4 v = *(const float4*)(x + i);
    ushort4 o;
    o.x = f2bf(v.x); o.y = f2bf(v.y); o.z = f2bf(v.z); o.w = f2bf(v.w);
    *(ushort4*)(xb + i) = o;
}

// ---------------- prep: both W transposes in one launch ----------------
// n < 768: Wqkv [256][768] -> wqkvT [768][256]; else Wproj [256][256] -> wprojT
__global__ __launch_bounds__(256) void k_transpose_w(const float* __restrict__ wqkv,
                                                     const float* __restrict__ wproj,
                                                     ushort* __restrict__ wqkvT,
                                                     ushort* __restrict__ wprojT) {
    int n = blockIdx.x * 256 + threadIdx.x;   // 0..1023
    int k = blockIdx.y;                       // 0..255
    if (n < 768) {
        wqkvT[n * 256 + k] = f2bf(wqkv[k * 768 + n]);
    } else {
        int m = n - 768;
        wprojT[m * 256 + k] = f2bf(wproj[k * 256 + m]);
    }
}

// ---------------- QKV GEMM: [8192x256]bf16 @ Wt[768][256] + bias ----------------
// writes HEAD-MAJOR buffers so attention tiles are CONTIGUOUS in memory:
//   qh[bh][n][32] = Q*(1/16), kh[bh][n][32] = K,
//   vT[bh][dh][4096] with columns permuted within each 64-block by
//   sigma^-1(s) = bits {s5,s3,s2,s4,s1,s0} (register-direct PV path).
__global__ __launch_bounds__(256) void k_qkv(const ushort* __restrict__ xb,
                                             const ushort* __restrict__ wt,
                                             const float* __restrict__ bias,
                                             ushort* __restrict__ qh,
                                             ushort* __restrict__ kh,
                                             ushort* __restrict__ vT) {
    int w = threadIdx.x >> 6, lane = threadIdx.x & 63;
    int lhi = lane >> 4, llo = lane & 15;
    int row0 = blockIdx.x * 64 + w * 16;
    int n0 = blockIdx.y * 64;

    f32x4 acc[4] = {};
#pragma unroll
    for (int ks = 0; ks < 8; ++ks) {
        int k0 = ks * 32 + lhi * 8;
        bf16x8 a = *(const bf16x8*)(xb + (row0 + llo) * 256 + k0);
#pragma unroll
        for (int fn = 0; fn < 4; ++fn) {
            bf16x8 b = *(const bf16x8*)(wt + (n0 + fn * 16 + llo) * 256 + k0);
            acc[fn] = __builtin_amdgcn_mfma_f32_16x16x32_bf16(a, b, acc[fn], 0, 0, 0);
        }
    }
#pragma unroll
    for (int fn = 0; fn < 4; ++fn) {
        int cg = n0 + fn * 16 + llo;
        int three = cg >> 8, rem = cg & 255;
        int hh = rem >> 5, dh = rem & 31;
        float bv = bias[cg];
#pragma unroll
        for (int r = 0; r < 4; ++r) {
            int row = row0 + lhi * 4 + r;
            float v = acc[fn][r] + bv;
            int bb = row >> 12, n = row & 4095;
            size_t hb = (size_t)(bb * NH + hh);
            if (three == 0) {
                qh[(hb * 4096 + n) * 32 + dh] = f2bf(v * 0.0625f);  // Q * C^-0.5
            } else if (three == 1) {
                kh[(hb * 4096 + n) * 32 + dh] = f2bf(v);
            } else {
                int s = n & 63;
                int np = (n & ~63) | ((s >> 5) << 5) | (((s & 15) >> 2) << 3)
                       | (((s >> 4) & 1) << 2) | (s & 3);
                vT[(hb * DHD + dh) * NSEQ + np] = f2bf(v);
            }
        }
    }
}

// ---------------- flash attention: block = 4 waves = 4 q-tiles of ONE head ----------------
// r9 staging structure + this round: 2 tiles per barrier-pair (halved barrier
// count, ~2 tiles of prefetch cover), s_setprio around MFMA clusters (T5),
// v_max3 max tree. Per-wave math identical to r9 (passed).
__global__ __launch_bounds__(256) void k_attn(const ushort* __restrict__ qh,
                                              const ushort* __restrict__ kh,
                                              const ushort* __restrict__ vT,
                                              ushort* __restrict__ attn_out) {
    __shared__ __align__(16) ushort Klds[2][64][40];   // 64 keys x 32 dh, rows padded to 80B
    __shared__ __align__(16) ushort Vlds[2][32][72];   // 32 dh x 64 keys, rows padded to 144B
    int t = threadIdx.x;
    int w = t >> 6, lane = t & 63;
    int lhi = lane >> 4, llo = lane & 15;
    // XCD swizzle: bid%8 = XCD; give each XCD 2 bh slices (Q+K+V ~1.5MB, L2-fit).
    int xcd = blockIdx.x & 7, qp = blockIdx.x >> 3;    // qp 0..127
    int bh = xcd * 2 + (qp >> 6);
    int qblk = qp & 63;
    int b = bh >> 3, h = bh & 7;
    int q0 = qblk * 64 + w * 16;

    const ushort* qbase = qh + (size_t)bh * 4096 * 32;
    // staging pointers for this thread (coalesced: 256 thr x 16B = full tile)
    const ushort* kg = kh + (size_t)bh * 4096 * 32 + (t >> 2) * 32 + (t & 3) * 8;
    const ushort* vg = vT + (size_t)bh * 32 * 4096 + (t >> 3) * 4096 + (t & 7) * 8;
    ushort* klp = &Klds[0][t >> 2][(t & 3) * 8];
    ushort* vlp = &Vlds[0][t >> 3][(t & 7) * 8];
    const int KLB = 64 * 40, VLB = 32 * 72;            // buffer strides (ushorts)

    bf16x8 qf = *(const bf16x8*)(qbase + (q0 + llo) * 32 + lhi * 8);
    short onebits = (llo == 0) ? (short)0x3F80 : (short)0;
    bf16x8 va2 = {onebits, onebits, onebits, onebits, onebits, onebits, onebits, onebits};

    f32x4 acc0 = {}, acc1 = {}, acc2 = {};
    const float L2E = 1.4426950408889634f;
    float mrun = 0.f, nmL2E = 0.f, mthr = 8.f;
    const f32x4 zf = {0.f, 0.f, 0.f, 0.f};

    // one 64-key tile from LDS buffer `cur`
    auto COMPUTE = [&](int cur) {
        const ushort* Kb = &Klds[cur][0][0];
        const ushort* Vb = &Vlds[cur][0][0];
        bf16x8 k0 = *(const bf16x8*)(Kb + (llo) * 40 + lhi * 8);
        bf16x8 k1 = *(const bf16x8*)(Kb + (16 + llo) * 40 + lhi * 8);
        bf16x8 k2 = *(const bf16x8*)(Kb + (32 + llo) * 40 + lhi * 8);
        bf16x8 k3 = *(const bf16x8*)(Kb + (48 + llo) * 40 + lhi * 8);
        bf16x8 v00 = *(const bf16x8*)(Vb + llo * 72 + lhi * 8);
        bf16x8 v01 = *(const bf16x8*)(Vb + (llo + 16) * 72 + lhi * 8);
        bf16x8 v10 = *(const bf16x8*)(Vb + llo * 72 + 32 + lhi * 8);
        bf16x8 v11 = *(const bf16x8*)(Vb + (llo + 16) * 72 + 32 + lhi * 8);
        // ---- S^T MFMA cluster (prioritized)
        __builtin_amdgcn_s_setprio(1);
        f32x4 sf0 = __builtin_amdgcn_mfma_f32_16x16x32_bf16(k0, qf, zf, 0, 0, 0);
        f32x4 sf1 = __builtin_amdgcn_mfma_f32_16x16x32_bf16(k1, qf, zf, 0, 0, 0);
        f32x4 sf2 = __builtin_amdgcn_mfma_f32_16x16x32_bf16(k2, qf, zf, 0, 0, 0);
        f32x4 sf3 = __builtin_amdgcn_mfma_f32_16x16x32_bf16(k3, qf, zf, 0, 0, 0);
        __builtin_amdgcn_s_setprio(0);
        // ---- deferred-max check: v_max3 tree (8 ops) + ballot
        float g0 = fmaxf(fmaxf(sf0[0], sf0[1]), sf0[2]);
        float g1 = fmaxf(fmaxf(sf0[3], sf1[0]), sf1[1]);
        float g2 = fmaxf(fmaxf(sf1[2], sf1[3]), sf2[0]);
        float g3 = fmaxf(fmaxf(sf2[1], sf2[2]), sf2[3]);
        float g4 = fmaxf(fmaxf(sf3[0], sf3[1]), sf3[2]);
        float h0 = fmaxf(fmaxf(g0, g1), g2);
        float h1 = fmaxf(fmaxf(g3, g4), sf3[3]);
        float tm = fmaxf(h0, h1);
        if (!__all(tm <= mthr)) {
            float rmax = fmaxf(tm, __shfl_xor(tm, 16));
            rmax = fmaxf(rmax, __shfl_xor(rmax, 32));
            float mnew = fmaxf(mrun, rmax);
            float corr = __builtin_amdgcn_exp2f((mrun - mnew) * L2E);
            mrun = mnew; nmL2E = -mrun * L2E; mthr = mrun + 8.f;
#pragma unroll
            for (int r = 0; r < 4; ++r) {
                float fc = __shfl(corr, lhi * 4 + r);
                acc0[r] *= fc; acc1[r] *= fc; acc2[r] *= fc;
            }
        }
        // ---- P = exp2(S*L2E - m*L2E); pack via v_cvt_pk_bf16_f32
        float e00 = __builtin_amdgcn_exp2f(__builtin_fmaf(sf0[0], L2E, nmL2E));
        float e01 = __builtin_amdgcn_exp2f(__builtin_fmaf(sf0[1], L2E, nmL2E));
        float e02 = __builtin_amdgcn_exp2f(__builtin_fmaf(sf0[2], L2E, nmL2E));
        float e03 = __builtin_amdgcn_exp2f(__builtin_fmaf(sf0[3], L2E, nmL2E));
        float e10 = __builtin_amdgcn_exp2f(__builtin_fmaf(sf1[0], L2E, nmL2E));
        float e11 = __builtin_amdgcn_exp2f(__builtin_fmaf(sf1[1], L2E, nmL2E));
        float e12 = __builtin_amdgcn_exp2f(__builtin_fmaf(sf1[2], L2E, nmL2E));
        float e13 = __builtin_amdgcn_exp2f(__builtin_fmaf(sf1[3], L2E, nmL2E));
        float e20 = __builtin_amdgcn_exp2f(__builtin_fmaf(sf2[0], L2E, nmL2E));
        float e21 = __builtin_amdgcn_exp2f(__builtin_fmaf(sf2[1], L2E, nmL2E));
        float e22 = __builtin_amdgcn_exp2f(__builtin_fmaf(sf2[2], L2E, nmL2E));
        float e23 = __builtin_amdgcn_exp2f(__builtin_fmaf(sf2[3], L2E, nmL2E));
        float e30 = __builtin_amdgcn_exp2f(__builtin_fmaf(sf3[0], L2E, nmL2E));
        float e31 = __builtin_amdgcn_exp2f(__builtin_fmaf(sf3[1], L2E, nmL2E));
        float e32 = __builtin_amdgcn_exp2f(__builtin_fmaf(sf3[2], L2E, nmL2E));
        float e33 = __builtin_amdgcn_exp2f(__builtin_fmaf(sf3[3], L2E, nmL2E));
        union PU { uint u[4]; bf16x8 v; };
        PU pa0, pa1;
        asm("v_cvt_pk_bf16_f32 %0, %1, %2" : "=v"(pa0.u[0]) : "v"(e00), "v"(e01));
        asm("v_cvt_pk_bf16_f32 %0, %1, %2" : "=v"(pa0.u[1]) : "v"(e02), "v"(e03));
        asm("v_cvt_pk_bf16_f32 %0, %1, %2" : "=v"(pa0.u[2]) : "v"(e10), "v"(e11));
        asm("v_cvt_pk_bf16_f32 %0, %1, %2" : "=v"(pa0.u[3]) : "v"(e12), "v"(e13));
        asm("v_cvt_pk_bf16_f32 %0, %1, %2" : "=v"(pa1.u[0]) : "v"(e20), "v"(e21));
        asm("v_cvt_pk_bf16_f32 %0, %1, %2" : "=v"(pa1.u[1]) : "v"(e22), "v"(e23));
        asm("v_cvt_pk_bf16_f32 %0, %1, %2" : "=v"(pa1.u[2]) : "v"(e30), "v"(e31));
        asm("v_cvt_pk_bf16_f32 %0, %1, %2" : "=v"(pa1.u[3]) : "v"(e32), "v"(e33));
        // ---- PV MFMA cluster (prioritized)
        __builtin_amdgcn_s_setprio(1);
        acc0 = __builtin_amdgcn_mfma_f32_16x16x32_bf16(pa0.v, v00, acc0, 0, 0, 0);
        acc1 = __builtin_amdgcn_mfma_f32_16x16x32_bf16(pa0.v, v01, acc1, 0, 0, 0);
        acc2 = __builtin_amdgcn_mfma_f32_16x16x32_bf16(pa0.v, va2, acc2, 0, 0, 0);
        acc0 = __builtin_amdgcn_mfma_f32_16x16x32_bf16(pa1.v, v10, acc0, 0, 0, 0);
        acc1 = __builtin_amdgcn_mfma_f32_16x16x32_bf16(pa1.v, v11, acc1, 0, 0, 0);
        acc2 = __builtin_amdgcn_mfma_f32_16x16x32_bf16(pa1.v, va2, acc2, 0, 0, 0);
        __builtin_amdgcn_s_setprio(0);
    };

    // prologue: stage tiles 0 and 1 into both buffers
    {
        bf16x8 ka = *(const bf16x8*)(kg);
        bf16x8 va = *(const bf16x8*)(vg);
        bf16x8 kb = *(const bf16x8*)(kg + 2048);
        bf16x8 vb = *(const bf16x8*)(vg + 64);
        *(bf16x8*)(klp) = ka;
        *(bf16x8*)(vlp) = va;
        *(bf16x8*)(klp + KLB) = kb;
        *(bf16x8*)(vlp + VLB) = vb;
    }
    __syncthreads();

#pragma unroll 1
    for (int it = 0; it < 32; ++it) {
        // prefetch the NEXT pair of tiles (issued before ~2 tiles of compute)
        bf16x8 ksA, vsA, ksB, vsB;
        if (it + 1 < 32) {
            int tn = 2 * it + 2;
            ksA = *(const bf16x8*)(kg + (size_t)tn * 2048);
            vsA = *(const bf16x8*)(vg + tn * 64);
            ksB = *(const bf16x8*)(kg + (size_t)(tn + 1) * 2048);
            vsB = *(const bf16x8*)(vg + (tn + 1) * 64);
        }
        COMPUTE(0);   // tile 2*it
        COMPUTE(1);   // tile 2*it+1
        __syncthreads();
        if (it + 1 < 32) {
            *(bf16x8*)(klp) = ksA;
            *(bf16x8*)(vlp) = vsA;
            *(bf16x8*)(klp + KLB) = ksB;
            *(bf16x8*)(vlp + VLB) = vsB;
            __syncthreads();
        }
    }

    // epilogue: l[q-row lhi*4+r] lives in acc2[r] of lane lhi*16 (col 0)
#pragma unroll
    for (int r = 0; r < 4; ++r) {
        float ls = __shfl(acc2[r], lhi * 16);
        float li = 1.f / ls;
        int row = q0 + lhi * 4 + r;
        size_t orow = ((size_t)(b * NSEQ) + row) * 256 + h * DHD;
        attn_out[orow + llo] = f2bf(acc0[r] * li);
        attn_out[orow + 16 + llo] = f2bf(acc1[r] * li);
    }
}

// ---------------- proj GEMM: [8192x256]bf16 @ Wt[256][256] + bias -> fp32 ----------------
__global__ __launch_bounds__(256) void k_proj(const ushort* __restrict__ aout,
                                              const ushort* __restrict__ wt,
                                              const float* __restrict__ bias,
                                              float* __restrict__ out) {
    int w = threadIdx.x >> 6, lane = threadIdx.x & 63;
    int lhi = lane >> 4, llo = lane & 15;
    int row0 = blockIdx.x * 64 + w * 16;
    int n0 = blockIdx.y * 64;

    f32x4 acc[4] = {};
#pragma unroll
    for (int ks = 0; ks < 8; ++ks) {
        int k0 = ks * 32 + lhi * 8;
        bf16x8 a = *(const bf16x8*)(aout + (row0 + llo) * 256 + k0);
#pragma unroll
        for (int fn = 0; fn < 4; ++fn) {
            bf16x8 b = *(const bf16x8*)(wt + (n0 + fn * 16 + llo) * 256 + k0);
            acc[fn] = __builtin_amdgcn_mfma_f32_16x16x32_bf16(a, b, acc[fn], 0, 0, 0);
        }
    }
#pragma unroll
    for (int fn = 0; fn < 4; ++fn) {
        int cg = n0 + fn * 16 + llo;
        float bv = bias[cg];
#pragma unroll
        for (int r = 0; r < 4; ++r) {
            int row = row0 + lhi * 4 + r;
            out[(size_t)row * 256 + cg] = acc[fn][r] + bv;
        }
    }
}

extern "C" void kernel_launch(void* const* d_in, const int* in_sizes, int n_in,
                              void* d_out, int out_size, void* d_ws, size_t ws_size,
                              hipStream_t stream) {
    const float* x     = (const float*)d_in[0];
    const float* Wqkv  = (const float*)d_in[1];
    const float* bqkv  = (const float*)d_in[2];
    const float* Wproj = (const float*)d_in[3];
    const float* bproj = (const float*)d_in[4];
    float* out = (float*)d_out;

    char* ws = (char*)d_ws;
    ushort* xb     = (ushort*)(ws);                 // 8192*256*2   = 4,194,304
    ushort* wqkvT  = (ushort*)(ws + 4194304);       // 768*256*2    =   393,216
    ushort* wprojT = (ushort*)(ws + 4587520);       // 256*256*2    =   131,072
    ushort* qhb    = (ushort*)(ws + 4718592);       // 16*4096*32*2 = 4,194,304
    ushort* khb    = (ushort*)(ws + 8912896);       // 16*4096*32*2 = 4,194,304
    ushort* vT     = (ushort*)(ws + 13107200);      // 16*32*4096*2 = 4,194,304
    ushort* aoutb  = (ushort*)(ws + 17301504);      // 8192*256*2   = 4,194,304
    // total ws use: 21,495,808 bytes (proven-safe size)

    k_convert_x<<<2048, 256, 0, stream>>>(x, xb);
    k_transpose_w<<<dim3(4, 256), 256, 0, stream>>>(Wqkv, Wproj, wqkvT, wprojT);
    k_qkv<<<dim3(128, 12), 256, 0, stream>>>(xb, wqkvT, bqkv, qhb, khb, vT);
    k_attn<<<1024, 256, 0, stream>>>(qhb, khb, vT, aoutb);
    k_proj<<<dim3(128, 4), 256, 0, stream>>>(aoutb, wprojT, bproj, out);
}

// Round 11
// 96.407 us; speedup vs baseline: 5.2396x; 1.3614x over previous
//
#include <hip/hip_runtime.h>

#define NSEQ 4096
#define BATCH 2
#define ROWS (BATCH * NSEQ)   // 8192
#define NH 8
#define DHD 32

typedef __attribute__((ext_vector_type(8))) short bf16x8;
typedef __attribute__((ext_vector_type(4))) float f32x4;

static __device__ __forceinline__ ushort f2bf(float f) {
    union { float f; uint u; } v; v.f = f;
    uint u = v.u;
    uint r = (u + 0x7fffu + ((u >> 16) & 1u)) >> 16;   // RTNE
    return (ushort)r;
}

// ---------------- prep: x convert + both W transposes, ONE launch ----------------
// bid < 2048: x fp32 -> bf16 (float4/ushort4). bid >= 2048: tiled 32x32 LDS
// transpose of Wqkv (24 n-tiles) and Wproj (8 n-tiles) x 8 k-tiles.
__global__ __launch_bounds__(256) void k_prep(const float* __restrict__ x,
                                              ushort* __restrict__ xb,
                                              const float* __restrict__ wqkv,
                                              const float* __restrict__ wproj,
                                              ushort* __restrict__ wqkvT,
                                              ushort* __restrict__ wprojT) {
    __shared__ float tile[32][33];
    int bid = blockIdx.x;
    if (bid < 2048) {
        int i = (bid * 256 + threadIdx.x) * 4;
        float4 v = *(const float4*)(x + i);
        ushort4 o;
        o.x = f2bf(v.x); o.y = f2bf(v.y); o.z = f2bf(v.z); o.w = f2bf(v.w);
        *(ushort4*)(xb + i) = o;
        return;   // block-uniform branch
    }
    int tb = bid - 2048;                 // 0..255
    int nt = tb & 31, kt = tb >> 5;      // 32 n-tiles, 8 k-tiles
    const float* src; ushort* dst; int ncols, nbase;
    if (nt < 24) { src = wqkv;  dst = wqkvT;  ncols = 768; nbase = nt * 32; }
    else         { src = wproj; dst = wprojT; ncols = 256; nbase = (nt - 24) * 32; }
    int tx = threadIdx.x & 31, ty = threadIdx.x >> 5;   // 32 x 8
#pragma unroll
    for (int j = 0; j < 4; ++j)
        tile[ty + j * 8][tx] = src[(size_t)(kt * 32 + ty + j * 8) * ncols + nbase + tx];
    __syncthreads();
#pragma unroll
    for (int j = 0; j < 4; ++j)
        dst[(size_t)(nbase + ty + j * 8) * 256 + kt * 32 + tx] = f2bf(tile[tx][ty + j * 8]);
}

// ---------------- QKV GEMM: LDS-staged tiles (coalesced loads), head-major out ----------------
// qh[bh][n][32] = Q*(1/16), kh[bh][n][32] = K,
// vT[bh][dh][4096] (sigma^-1-permuted cols) written via LDS transpose: coalesced.
__global__ __launch_bounds__(256) void k_qkv(const ushort* __restrict__ xb,
                                             const ushort* __restrict__ wt,
                                             const float* __restrict__ bias,
                                             ushort* __restrict__ qh,
                                             ushort* __restrict__ kh,
                                             ushort* __restrict__ vT) {
    __shared__ __align__(16) ushort Al[64][264];   // rows padded to 528B = 33 super-banks
    __shared__ __align__(16) ushort Bl[64][264];
    int t = threadIdx.x;
    int w = t >> 6, lane = t & 63;
    int lhi = lane >> 4, llo = lane & 15;
    int row0 = blockIdx.x * 64;
    int n0 = blockIdx.y * 64;

    // stage A (x rows) and B (wt rows): 256 thr x 16B per instr, fully coalesced
#pragma unroll
    for (int j = 0; j < 8; ++j) {
        int f = j * 256 + t;             // 0..2047 chunks of 16B
        int r = f >> 5, c = (f & 31) * 8;
        *(bf16x8*)&Al[r][c] = *(const bf16x8*)(xb + (size_t)(row0 + r) * 256 + c);
        *(bf16x8*)&Bl[r][c] = *(const bf16x8*)(wt + (size_t)(n0 + r) * 256 + c);
    }
    __syncthreads();

    f32x4 acc[4] = {};
#pragma unroll
    for (int ks = 0; ks < 8; ++ks) {
        int k0 = ks * 32 + lhi * 8;
        bf16x8 a = *(const bf16x8*)&Al[w * 16 + llo][k0];
#pragma unroll
        for (int fn = 0; fn < 4; ++fn) {
            bf16x8 b = *(const bf16x8*)&Bl[fn * 16 + llo][k0];
            acc[fn] = __builtin_amdgcn_mfma_f32_16x16x32_bf16(a, b, acc[fn], 0, 0, 0);
        }
    }

    int bb = row0 >> 12;          // batch index
    int nb = row0 & 4095;         // seq base (64-aligned)
    if (blockIdx.y < 8) {
        // ---- Q / K epilogue: 16-lane 32B runs (fine)
#pragma unroll
        for (int fn = 0; fn < 4; ++fn) {
            int cg = n0 + fn * 16 + llo;
            int three = cg >> 8, rem = cg & 255;
            int hh = rem >> 5, dh = rem & 31;
            float bv = bias[cg];
            size_t hb = (size_t)(bb * NH + hh);
#pragma unroll
            for (int r = 0; r < 4; ++r) {
                int n = nb + w * 16 + lhi * 4 + r;
                float v = acc[fn][r] + bv;
                if (three == 0) qh[(hb * 4096 + (size_t)n) * 32 + dh] = f2bf(v * 0.0625f);
                else            kh[(hb * 4096 + (size_t)n) * 32 + dh] = f2bf(v);
            }
        }
    } else {
        // ---- V epilogue: LDS transpose (reuse Al), sigma^-1 applied on store side,
        // then coalesced b128 global writes.
        __syncthreads();                  // all waves done reading Al/Bl
        ushort (*vbuf)[68] = (ushort(*)[68])&Al[0][0];   // 64 x 68 fits in Al
#pragma unroll
        for (int fn = 0; fn < 4; ++fn) {
            int c = fn * 16 + llo;
            float bv = bias[n0 + c];
#pragma unroll
            for (int r = 0; r < 4; ++r) {
                int s = w * 16 + lhi * 4 + r;
                int np = ((s >> 5) << 5) | (((s & 15) >> 2) << 3)
                       | (((s >> 4) & 1) << 2) | (s & 3);
                vbuf[c][np] = f2bf(acc[fn][r] + bv);
            }
        }
        __syncthreads();
#pragma unroll
        for (int j = 0; j < 2; ++j) {
            int f = j * 256 + t;          // 0..511 = 64 cols x 8 chunks
            int col = f >> 3, ch = (f & 7) * 8;
            bf16x8 val = *(const bf16x8*)&vbuf[col][ch];
            int dh = col & 31;
            int hh = ((int)blockIdx.y - 8) * 2 + (col >> 5);
            size_t hb = (size_t)(bb * NH + hh);
            *(bf16x8*)(vT + (hb * DHD + dh) * NSEQ + nb + ch) = val;
        }
    }
}

// ---------------- flash attention: UNCHANGED from round 10 (passed, 77 us) ----------------
__global__ __launch_bounds__(256) void k_attn(const ushort* __restrict__ qh,
                                              const ushort* __restrict__ kh,
                                              const ushort* __restrict__ vT,
                                              ushort* __restrict__ attn_out) {
    __shared__ __align__(16) ushort Klds[2][64][40];   // 64 keys x 32 dh, rows padded to 80B
    __shared__ __align__(16) ushort Vlds[2][32][72];   // 32 dh x 64 keys, rows padded to 144B
    int t = threadIdx.x;
    int w = t >> 6, lane = t & 63;
    int lhi = lane >> 4, llo = lane & 15;
    int xcd = blockIdx.x & 7, qp = blockIdx.x >> 3;    // qp 0..127
    int bh = xcd * 2 + (qp >> 6);
    int qblk = qp & 63;
    int b = bh >> 3, h = bh & 7;
    int q0 = qblk * 64 + w * 16;

    const ushort* qbase = qh + (size_t)bh * 4096 * 32;
    const ushort* kg = kh + (size_t)bh * 4096 * 32 + (t >> 2) * 32 + (t & 3) * 8;
    const ushort* vg = vT + (size_t)bh * 32 * 4096 + (t >> 3) * 4096 + (t & 7) * 8;
    ushort* klp = &Klds[0][t >> 2][(t & 3) * 8];
    ushort* vlp = &Vlds[0][t >> 3][(t & 7) * 8];
    const int KLB = 64 * 40, VLB = 32 * 72;

    bf16x8 qf = *(const bf16x8*)(qbase + (q0 + llo) * 32 + lhi * 8);
    short onebits = (llo == 0) ? (short)0x3F80 : (short)0;
    bf16x8 va2 = {onebits, onebits, onebits, onebits, onebits, onebits, onebits, onebits};

    f32x4 acc0 = {}, acc1 = {}, acc2 = {};
    const float L2E = 1.4426950408889634f;
    float mrun = 0.f, nmL2E = 0.f, mthr = 8.f;
    const f32x4 zf = {0.f, 0.f, 0.f, 0.f};

    auto COMPUTE = [&](int cur) {
        const ushort* Kb = &Klds[cur][0][0];
        const ushort* Vb = &Vlds[cur][0][0];
        bf16x8 k0 = *(const bf16x8*)(Kb + (llo) * 40 + lhi * 8);
        bf16x8 k1 = *(const bf16x8*)(Kb + (16 + llo) * 40 + lhi * 8);
        bf16x8 k2 = *(const bf16x8*)(Kb + (32 + llo) * 40 + lhi * 8);
        bf16x8 k3 = *(const bf16x8*)(Kb + (48 + llo) * 40 + lhi * 8);
        bf16x8 v00 = *(const bf16x8*)(Vb + llo * 72 + lhi * 8);
        bf16x8 v01 = *(const bf16x8*)(Vb + (llo + 16) * 72 + lhi * 8);
        bf16x8 v10 = *(const bf16x8*)(Vb + llo * 72 + 32 + lhi * 8);
        bf16x8 v11 = *(const bf16x8*)(Vb + (llo + 16) * 72 + 32 + lhi * 8);
        __builtin_amdgcn_s_setprio(1);
        f32x4 sf0 = __builtin_amdgcn_mfma_f32_16x16x32_bf16(k0, qf, zf, 0, 0, 0);
        f32x4 sf1 = __builtin_amdgcn_mfma_f32_16x16x32_bf16(k1, qf, zf, 0, 0, 0);
        f32x4 sf2 = __builtin_amdgcn_mfma_f32_16x16x32_bf16(k2, qf, zf, 0, 0, 0);
        f32x4 sf3 = __builtin_amdgcn_mfma_f32_16x16x32_bf16(k3, qf, zf, 0, 0, 0);
        __builtin_amdgcn_s_setprio(0);
        float g0 = fmaxf(fmaxf(sf0[0], sf0[1]), sf0[2]);
        float g1 = fmaxf(fmaxf(sf0[3], sf1[0]), sf1[1]);
        float g2 = fmaxf(fmaxf(sf1[2], sf1[3]), sf2[0]);
        float g3 = fmaxf(fmaxf(sf2[1], sf2[2]), sf2[3]);
        float g4 = fmaxf(fmaxf(sf3[0], sf3[1]), sf3[2]);
        float h0 = fmaxf(fmaxf(g0, g1), g2);
        float h1 = fmaxf(fmaxf(g3, g4), sf3[3]);
        float tm = fmaxf(h0, h1);
        if (!__all(tm <= mthr)) {
            float rmax = fmaxf(tm, __shfl_xor(tm, 16));
            rmax = fmaxf(rmax, __shfl_xor(rmax, 32));
            float mnew = fmaxf(mrun, rmax);
            float corr = __builtin_amdgcn_exp2f((mrun - mnew) * L2E);
            mrun = mnew; nmL2E = -mrun * L2E; mthr = mrun + 8.f;
#pragma unroll
            for (int r = 0; r < 4; ++r) {
                float fc = __shfl(corr, lhi * 4 + r);
                acc0[r] *= fc; acc1[r] *= fc; acc2[r] *= fc;
            }
        }
        float e00 = __builtin_amdgcn_exp2f(__builtin_fmaf(sf0[0], L2E, nmL2E));
        float e01 = __builtin_amdgcn_exp2f(__builtin_fmaf(sf0[1], L2E, nmL2E));
        float e02 = __builtin_amdgcn_exp2f(__builtin_fmaf(sf0[2], L2E, nmL2E));
        float e03 = __builtin_amdgcn_exp2f(__builtin_fmaf(sf0[3], L2E, nmL2E));
        float e10 = __builtin_amdgcn_exp2f(__builtin_fmaf(sf1[0], L2E, nmL2E));
        float e11 = __builtin_amdgcn_exp2f(__builtin_fmaf(sf1[1], L2E, nmL2E));
        float e12 = __builtin_amdgcn_exp2f(__builtin_fmaf(sf1[2], L2E, nmL2E));
        float e13 = __builtin_amdgcn_exp2f(__builtin_fmaf(sf1[3], L2E, nmL2E));
        float e20 = __builtin_amdgcn_exp2f(__builtin_fmaf(sf2[0], L2E, nmL2E));
        float e21 = __builtin_amdgcn_exp2f(__builtin_fmaf(sf2[1], L2E, nmL2E));
        float e22 = __builtin_amdgcn_exp2f(__builtin_fmaf(sf2[2], L2E, nmL2E));
        float e23 = __builtin_amdgcn_exp2f(__builtin_fmaf(sf2[3], L2E, nmL2E));
        float e30 = __builtin_amdgcn_exp2f(__builtin_fmaf(sf3[0], L2E, nmL2E));
        float e31 = __builtin_amdgcn_exp2f(__builtin_fmaf(sf3[1], L2E, nmL2E));
        float e32 = __builtin_amdgcn_exp2f(__builtin_fmaf(sf3[2], L2E, nmL2E));
        float e33 = __builtin_amdgcn_exp2f(__builtin_fmaf(sf3[3], L2E, nmL2E));
        union PU { uint u[4]; bf16x8 v; };
        PU pa0, pa1;
        asm("v_cvt_pk_bf16_f32 %0, %1, %2" : "=v"(pa0.u[0]) : "v"(e00), "v"(e01));
        asm("v_cvt_pk_bf16_f32 %0, %1, %2" : "=v"(pa0.u[1]) : "v"(e02), "v"(e03));
        asm("v_cvt_pk_bf16_f32 %0, %1, %2" : "=v"(pa0.u[2]) : "v"(e10), "v"(e11));
        asm("v_cvt_pk_bf16_f32 %0, %1, %2" : "=v"(pa0.u[3]) : "v"(e12), "v"(e13));
        asm("v_cvt_pk_bf16_f32 %0, %1, %2" : "=v"(pa1.u[0]) : "v"(e20), "v"(e21));
        asm("v_cvt_pk_bf16_f32 %0, %1, %2" : "=v"(pa1.u[1]) : "v"(e22), "v"(e23));
        asm("v_cvt_pk_bf16_f32 %0, %1, %2" : "=v"(pa1.u[2]) : "v"(e30), "v"(e31));
        asm("v_cvt_pk_bf16_f32 %0, %1, %2" : "=v"(pa1.u[3]) : "v"(e32), "v"(e33));
        __builtin_amdgcn_s_setprio(1);
        acc0 = __builtin_amdgcn_mfma_f32_16x16x32_bf16(pa0.v, v00, acc0, 0, 0, 0);
        acc1 = __builtin_amdgcn_mfma_f32_16x16x32_bf16(pa0.v, v01, acc1, 0, 0, 0);
        acc2 = __builtin_amdgcn_mfma_f32_16x16x32_bf16(pa0.v, va2, acc2, 0, 0, 0);
        acc0 = __builtin_amdgcn_mfma_f32_16x16x32_bf16(pa1.v, v10, acc0, 0, 0, 0);
        acc1 = __builtin_amdgcn_mfma_f32_16x16x32_bf16(pa1.v, v11, acc1, 0, 0, 0);
        acc2 = __builtin_amdgcn_mfma_f32_16x16x32_bf16(pa1.v, va2, acc2, 0, 0, 0);
        __builtin_amdgcn_s_setprio(0);
    };

    {
        bf16x8 ka = *(const bf16x8*)(kg);
        bf16x8 va = *(const bf16x8*)(vg);
        bf16x8 kb = *(const bf16x8*)(kg + 2048);
        bf16x8 vb = *(const bf16x8*)(vg + 64);
        *(bf16x8*)(klp) = ka;
        *(bf16x8*)(vlp) = va;
        *(bf16x8*)(klp + KLB) = kb;
        *(bf16x8*)(vlp + VLB) = vb;
    }
    __syncthreads();

#pragma unroll 1
    for (int it = 0; it < 32; ++it) {
        bf16x8 ksA, vsA, ksB, vsB;
        if (it + 1 < 32) {
            int tn = 2 * it + 2;
            ksA = *(const bf16x8*)(kg + (size_t)tn * 2048);
            vsA = *(const bf16x8*)(vg + tn * 64);
            ksB = *(const bf16x8*)(kg + (size_t)(tn + 1) * 2048);
            vsB = *(const bf16x8*)(vg + (tn + 1) * 64);
        }
        COMPUTE(0);
        COMPUTE(1);
        __syncthreads();
        if (it + 1 < 32) {
            *(bf16x8*)(klp) = ksA;
            *(bf16x8*)(vlp) = vsA;
            *(bf16x8*)(klp + KLB) = ksB;
            *(bf16x8*)(vlp + VLB) = vsB;
            __syncthreads();
        }
    }

#pragma unroll
    for (int r = 0; r < 4; ++r) {
        float ls = __shfl(acc2[r], lhi * 16);
        float li = 1.f / ls;
        int row = q0 + lhi * 4 + r;
        size_t orow = ((size_t)(b * NSEQ) + row) * 256 + h * DHD;
        attn_out[orow + llo] = f2bf(acc0[r] * li);
        attn_out[orow + 16 + llo] = f2bf(acc1[r] * li);
    }
}

// ---------------- proj GEMM: LDS-staged tiles (coalesced loads) ----------------
__global__ __launch_bounds__(256) void k_proj(const ushort* __restrict__ aout,
                                              const ushort* __restrict__ wt,
                                              const float* __restrict__ bias,
                                              float* __restrict__ out) {
    __shared__ __align__(16) ushort Al[64][264];
    __shared__ __align__(16) ushort Bl[64][264];
    int t = threadIdx.x;
    int w = t >> 6, lane = t & 63;
    int lhi = lane >> 4, llo = lane & 15;
    int row0 = blockIdx.x * 64;
    int n0 = blockIdx.y * 64;

#pragma unroll
    for (int j = 0; j < 8; ++j) {
        int f = j * 256 + t;
        int r = f >> 5, c = (f & 31) * 8;
        *(bf16x8*)&Al[r][c] = *(const bf16x8*)(aout + (size_t)(row0 + r) * 256 + c);
        *(bf16x8*)&Bl[r][c] = *(const bf16x8*)(wt + (size_t)(n0 + r) * 256 + c);
    }
    __syncthreads();

    f32x4 acc[4] = {};
#pragma unroll
    for (int ks = 0; ks < 8; ++ks) {
        int k0 = ks * 32 + lhi * 8;
        bf16x8 a = *(const bf16x8*)&Al[w * 16 + llo][k0];
#pragma unroll
        for (int fn = 0; fn < 4; ++fn) {
            bf16x8 b = *(const bf16x8*)&Bl[fn * 16 + llo][k0];
            acc[fn] = __builtin_amdgcn_mfma_f32_16x16x32_bf16(a, b, acc[fn], 0, 0, 0);
        }
    }
#pragma unroll
    for (int fn = 0; fn < 4; ++fn) {
        int cg = n0 + fn * 16 + llo;
        float bv = bias[cg];
#pragma unroll
        for (int r = 0; r < 4; ++r) {
            int row = row0 + w * 16 + lhi * 4 + r;
            out[(size_t)row * 256 + cg] = acc[fn][r] + bv;
        }
    }
}

extern "C" void kernel_launch(void* const* d_in, const int* in_sizes, int n_in,
                              void* d_out, int out_size, void* d_ws, size_t ws_size,
                              hipStream_t stream) {
    const float* x     = (const float*)d_in[0];
    const float* Wqkv  = (const float*)d_in[1];
    const float* bqkv  = (const float*)d_in[2];
    const float* Wproj = (const float*)d_in[3];
    const float* bproj = (const float*)d_in[4];
    float* out = (float*)d_out;

    char* ws = (char*)d_ws;
    ushort* xb     = (ushort*)(ws);                 // 8192*256*2   = 4,194,304
    ushort* wqkvT  = (ushort*)(ws + 4194304);       // 768*256*2    =   393,216
    ushort* wprojT = (ushort*)(ws + 4587520);       // 256*256*2    =   131,072
    ushort* qhb    = (ushort*)(ws + 4718592);       // 16*4096*32*2 = 4,194,304
    ushort* khb    = (ushort*)(ws + 8912896);       // 16*4096*32*2 = 4,194,304
    ushort* vT     = (ushort*)(ws + 13107200);      // 16*32*4096*2 = 4,194,304
    ushort* aoutb  = (ushort*)(ws + 17301504);      // 8192*256*2   = 4,194,304
    // total ws use: 21,495,808 bytes (proven-safe size)

    k_prep<<<2304, 256, 0, stream>>>(x, xb, Wqkv, Wproj, wqkvT, wprojT);
    k_qkv<<<dim3(128, 12), 256, 0, stream>>>(xb, wqkvT, bqkv, qhb, khb, vT);
    k_attn<<<1024, 256, 0, stream>>>(qhb, khb, vT, aoutb);
    k_proj<<<dim3(128, 4), 256, 0, stream>>>(aoutb, wprojT, bproj, out);
}

// Round 12
// 93.996 us; speedup vs baseline: 5.3740x; 1.0256x over previous
//
#include <hip/hip_runtime.h>

#define NSEQ 4096
#define BATCH 2
#define ROWS (BATCH * NSEQ)   // 8192
#define NH 8
#define DHD 32

typedef __attribute__((ext_vector_type(8))) short bf16x8;
typedef __attribute__((ext_vector_type(4))) float f32x4;

static __device__ __forceinline__ ushort f2bf(float f) {
    union { float f; uint u; } v; v.f = f;
    uint u = v.u;
    uint r = (u + 0x7fffu + ((u >> 16) & 1u)) >> 16;   // RTNE
    return (ushort)r;
}

// ---------------- prep: x convert + both W transposes, ONE launch ----------------
__global__ __launch_bounds__(256) void k_prep(const float* __restrict__ x,
                                              ushort* __restrict__ xb,
                                              const float* __restrict__ wqkv,
                                              const float* __restrict__ wproj,
                                              ushort* __restrict__ wqkvT,
                                              ushort* __restrict__ wprojT) {
    __shared__ float tile[32][33];
    int bid = blockIdx.x;
    if (bid < 2048) {
        int i = (bid * 256 + threadIdx.x) * 4;
        float4 v = *(const float4*)(x + i);
        ushort4 o;
        o.x = f2bf(v.x); o.y = f2bf(v.y); o.z = f2bf(v.z); o.w = f2bf(v.w);
        *(ushort4*)(xb + i) = o;
        return;   // block-uniform branch
    }
    int tb = bid - 2048;                 // 0..255
    int nt = tb & 31, kt = tb >> 5;      // 32 n-tiles, 8 k-tiles
    const float* src; ushort* dst; int ncols, nbase;
    if (nt < 24) { src = wqkv;  dst = wqkvT;  ncols = 768; nbase = nt * 32; }
    else         { src = wproj; dst = wprojT; ncols = 256; nbase = (nt - 24) * 32; }
    int tx = threadIdx.x & 31, ty = threadIdx.x >> 5;   // 32 x 8
#pragma unroll
    for (int j = 0; j < 4; ++j)
        tile[ty + j * 8][tx] = src[(size_t)(kt * 32 + ty + j * 8) * ncols + nbase + tx];
    __syncthreads();
#pragma unroll
    for (int j = 0; j < 4; ++j)
        dst[(size_t)(nbase + ty + j * 8) * 256 + kt * 32 + tx] = f2bf(tile[tx][ty + j * 8]);
}

// ---------------- QKV GEMM: LDS-staged tiles, head-major out (r11, passed) ----------------
__global__ __launch_bounds__(256) void k_qkv(const ushort* __restrict__ xb,
                                             const ushort* __restrict__ wt,
                                             const float* __restrict__ bias,
                                             ushort* __restrict__ qh,
                                             ushort* __restrict__ kh,
                                             ushort* __restrict__ vT) {
    __shared__ __align__(16) ushort Al[64][264];   // rows padded to 528B = 33 super-banks
    __shared__ __align__(16) ushort Bl[64][264];
    int t = threadIdx.x;
    int w = t >> 6, lane = t & 63;
    int lhi = lane >> 4, llo = lane & 15;
    int row0 = blockIdx.x * 64;
    int n0 = blockIdx.y * 64;

#pragma unroll
    for (int j = 0; j < 8; ++j) {
        int f = j * 256 + t;             // 0..2047 chunks of 16B
        int r = f >> 5, c = (f & 31) * 8;
        *(bf16x8*)&Al[r][c] = *(const bf16x8*)(xb + (size_t)(row0 + r) * 256 + c);
        *(bf16x8*)&Bl[r][c] = *(const bf16x8*)(wt + (size_t)(n0 + r) * 256 + c);
    }
    __syncthreads();

    f32x4 acc[4] = {};
#pragma unroll
    for (int ks = 0; ks < 8; ++ks) {
        int k0 = ks * 32 + lhi * 8;
        bf16x8 a = *(const bf16x8*)&Al[w * 16 + llo][k0];
#pragma unroll
        for (int fn = 0; fn < 4; ++fn) {
            bf16x8 b = *(const bf16x8*)&Bl[fn * 16 + llo][k0];
            acc[fn] = __builtin_amdgcn_mfma_f32_16x16x32_bf16(a, b, acc[fn], 0, 0, 0);
        }
    }

    int bb = row0 >> 12;          // batch index
    int nb = row0 & 4095;         // seq base (64-aligned)
    if (blockIdx.y < 8) {
#pragma unroll
        for (int fn = 0; fn < 4; ++fn) {
            int cg = n0 + fn * 16 + llo;
            int three = cg >> 8, rem = cg & 255;
            int hh = rem >> 5, dh = rem & 31;
            float bv = bias[cg];
            size_t hb = (size_t)(bb * NH + hh);
#pragma unroll
            for (int r = 0; r < 4; ++r) {
                int n = nb + w * 16 + lhi * 4 + r;
                float v = acc[fn][r] + bv;
                if (three == 0) qh[(hb * 4096 + (size_t)n) * 32 + dh] = f2bf(v * 0.0625f);
                else            kh[(hb * 4096 + (size_t)n) * 32 + dh] = f2bf(v);
            }
        }
    } else {
        __syncthreads();                  // all waves done reading Al/Bl
        ushort (*vbuf)[68] = (ushort(*)[68])&Al[0][0];   // 64 x 68 fits in Al
#pragma unroll
        for (int fn = 0; fn < 4; ++fn) {
            int c = fn * 16 + llo;
            float bv = bias[n0 + c];
#pragma unroll
            for (int r = 0; r < 4; ++r) {
                int s = w * 16 + lhi * 4 + r;
                int np = ((s >> 5) << 5) | (((s & 15) >> 2) << 3)
                       | (((s >> 4) & 1) << 2) | (s & 3);
                vbuf[c][np] = f2bf(acc[fn][r] + bv);
            }
        }
        __syncthreads();
#pragma unroll
        for (int j = 0; j < 2; ++j) {
            int f = j * 256 + t;          // 0..511 = 64 cols x 8 chunks
            int col = f >> 3, ch = (f & 7) * 8;
            bf16x8 val = *(const bf16x8*)&vbuf[col][ch];
            int dh = col & 31;
            int hh = ((int)blockIdx.y - 8) * 2 + (col >> 5);
            size_t hb = (size_t)(bb * NH + hh);
            *(bf16x8*)(vT + (hb * DHD + dh) * NSEQ + nb + ch) = val;
        }
    }
}

// ---------------- flash attention: 4-buffer rotating pipeline ----------------
// vs r10: barriers 64 -> 32 (2 per 4 tiles) and LDS writes overlapped with
// compute (no serial write region). COMPUTE math byte-identical to r10/r11.
__global__ __launch_bounds__(256) void k_attn(const ushort* __restrict__ qh,
                                              const ushort* __restrict__ kh,
                                              const ushort* __restrict__ vT,
                                              ushort* __restrict__ attn_out) {
    __shared__ __align__(16) ushort Klds[4][64][40];   // 4 bufs: 64 keys x 32 dh (+pad)
    __shared__ __align__(16) ushort Vlds[4][32][72];   // 4 bufs: 32 dh x 64 keys (+pad)
    int t = threadIdx.x;
    int w = t >> 6, lane = t & 63;
    int lhi = lane >> 4, llo = lane & 15;
    int xcd = blockIdx.x & 7, qp = blockIdx.x >> 3;    // qp 0..127
    int bh = xcd * 2 + (qp >> 6);
    int qblk = qp & 63;
    int b = bh >> 3, h = bh & 7;
    int q0 = qblk * 64 + w * 16;

    const ushort* qbase = qh + (size_t)bh * 4096 * 32;
    const ushort* kg = kh + (size_t)bh * 4096 * 32 + (t >> 2) * 32 + (t & 3) * 8;
    const ushort* vg = vT + (size_t)bh * 32 * 4096 + (t >> 3) * 4096 + (t & 7) * 8;
    ushort* klp = &Klds[0][t >> 2][(t & 3) * 8];
    ushort* vlp = &Vlds[0][t >> 3][(t & 7) * 8];
    const int KLB = 64 * 40, VLB = 32 * 72;            // per-buffer strides (ushorts)

    bf16x8 qf = *(const bf16x8*)(qbase + (q0 + llo) * 32 + lhi * 8);
    short onebits = (llo == 0) ? (short)0x3F80 : (short)0;
    bf16x8 va2 = {onebits, onebits, onebits, onebits, onebits, onebits, onebits, onebits};

    f32x4 acc0 = {}, acc1 = {}, acc2 = {};
    const float L2E = 1.4426950408889634f;
    float mrun = 0.f, nmL2E = 0.f, mthr = 8.f;
    const f32x4 zf = {0.f, 0.f, 0.f, 0.f};

    auto COMPUTE = [&](int cur) {
        const ushort* Kb = &Klds[cur][0][0];
        const ushort* Vb = &Vlds[cur][0][0];
        bf16x8 k0 = *(const bf16x8*)(Kb + (llo) * 40 + lhi * 8);
        bf16x8 k1 = *(const bf16x8*)(Kb + (16 + llo) * 40 + lhi * 8);
        bf16x8 k2 = *(const bf16x8*)(Kb + (32 + llo) * 40 + lhi * 8);
        bf16x8 k3 = *(const bf16x8*)(Kb + (48 + llo) * 40 + lhi * 8);
        bf16x8 v00 = *(const bf16x8*)(Vb + llo * 72 + lhi * 8);
        bf16x8 v01 = *(const bf16x8*)(Vb + (llo + 16) * 72 + lhi * 8);
        bf16x8 v10 = *(const bf16x8*)(Vb + llo * 72 + 32 + lhi * 8);
        bf16x8 v11 = *(const bf16x8*)(Vb + (llo + 16) * 72 + 32 + lhi * 8);
        __builtin_amdgcn_s_setprio(1);
        f32x4 sf0 = __builtin_amdgcn_mfma_f32_16x16x32_bf16(k0, qf, zf, 0, 0, 0);
        f32x4 sf1 = __builtin_amdgcn_mfma_f32_16x16x32_bf16(k1, qf, zf, 0, 0, 0);
        f32x4 sf2 = __builtin_amdgcn_mfma_f32_16x16x32_bf16(k2, qf, zf, 0, 0, 0);
        f32x4 sf3 = __builtin_amdgcn_mfma_f32_16x16x32_bf16(k3, qf, zf, 0, 0, 0);
        __builtin_amdgcn_s_setprio(0);
        float g0 = fmaxf(fmaxf(sf0[0], sf0[1]), sf0[2]);
        float g1 = fmaxf(fmaxf(sf0[3], sf1[0]), sf1[1]);
        float g2 = fmaxf(fmaxf(sf1[2], sf1[3]), sf2[0]);
        float g3 = fmaxf(fmaxf(sf2[1], sf2[2]), sf2[3]);
        float g4 = fmaxf(fmaxf(sf3[0], sf3[1]), sf3[2]);
        float h0 = fmaxf(fmaxf(g0, g1), g2);
        float h1 = fmaxf(fmaxf(g3, g4), sf3[3]);
        float tm = fmaxf(h0, h1);
        if (!__all(tm <= mthr)) {
            float rmax = fmaxf(tm, __shfl_xor(tm, 16));
            rmax = fmaxf(rmax, __shfl_xor(rmax, 32));
            float mnew = fmaxf(mrun, rmax);
            float corr = __builtin_amdgcn_exp2f((mrun - mnew) * L2E);
            mrun = mnew; nmL2E = -mrun * L2E; mthr = mrun + 8.f;
#pragma unroll
            for (int r = 0; r < 4; ++r) {
                float fc = __shfl(corr, lhi * 4 + r);
                acc0[r] *= fc; acc1[r] *= fc; acc2[r] *= fc;
            }
        }
        float e00 = __builtin_amdgcn_exp2f(__builtin_fmaf(sf0[0], L2E, nmL2E));
        float e01 = __builtin_amdgcn_exp2f(__builtin_fmaf(sf0[1], L2E, nmL2E));
        float e02 = __builtin_amdgcn_exp2f(__builtin_fmaf(sf0[2], L2E, nmL2E));
        float e03 = __builtin_amdgcn_exp2f(__builtin_fmaf(sf0[3], L2E, nmL2E));
        float e10 = __builtin_amdgcn_exp2f(__builtin_fmaf(sf1[0], L2E, nmL2E));
        float e11 = __builtin_amdgcn_exp2f(__builtin_fmaf(sf1[1], L2E, nmL2E));
        float e12 = __builtin_amdgcn_exp2f(__builtin_fmaf(sf1[2], L2E, nmL2E));
        float e13 = __builtin_amdgcn_exp2f(__builtin_fmaf(sf1[3], L2E, nmL2E));
        float e20 = __builtin_amdgcn_exp2f(__builtin_fmaf(sf2[0], L2E, nmL2E));
        float e21 = __builtin_amdgcn_exp2f(__builtin_fmaf(sf2[1], L2E, nmL2E));
        float e22 = __builtin_amdgcn_exp2f(__builtin_fmaf(sf2[2], L2E, nmL2E));
        float e23 = __builtin_amdgcn_exp2f(__builtin_fmaf(sf2[3], L2E, nmL2E));
        float e30 = __builtin_amdgcn_exp2f(__builtin_fmaf(sf3[0], L2E, nmL2E));
        float e31 = __builtin_amdgcn_exp2f(__builtin_fmaf(sf3[1], L2E, nmL2E));
        float e32 = __builtin_amdgcn_exp2f(__builtin_fmaf(sf3[2], L2E, nmL2E));
        float e33 = __builtin_amdgcn_exp2f(__builtin_fmaf(sf3[3], L2E, nmL2E));
        union PU { uint u[4]; bf16x8 v; };
        PU pa0, pa1;
        asm("v_cvt_pk_bf16_f32 %0, %1, %2" : "=v"(pa0.u[0]) : "v"(e00), "v"(e01));
        asm("v_cvt_pk_bf16_f32 %0, %1, %2" : "=v"(pa0.u[1]) : "v"(e02), "v"(e03));
        asm("v_cvt_pk_bf16_f32 %0, %1, %2" : "=v"(pa0.u[2]) : "v"(e10), "v"(e11));
        asm("v_cvt_pk_bf16_f32 %0, %1, %2" : "=v"(pa0.u[3]) : "v"(e12), "v"(e13));
        asm("v_cvt_pk_bf16_f32 %0, %1, %2" : "=v"(pa1.u[0]) : "v"(e20), "v"(e21));
        asm("v_cvt_pk_bf16_f32 %0, %1, %2" : "=v"(pa1.u[1]) : "v"(e22), "v"(e23));
        asm("v_cvt_pk_bf16_f32 %0, %1, %2" : "=v"(pa1.u[2]) : "v"(e30), "v"(e31));
        asm("v_cvt_pk_bf16_f32 %0, %1, %2" : "=v"(pa1.u[3]) : "v"(e32), "v"(e33));
        __builtin_amdgcn_s_setprio(1);
        acc0 = __builtin_amdgcn_mfma_f32_16x16x32_bf16(pa0.v, v00, acc0, 0, 0, 0);
        acc1 = __builtin_amdgcn_mfma_f32_16x16x32_bf16(pa0.v, v01, acc1, 0, 0, 0);
        acc2 = __builtin_amdgcn_mfma_f32_16x16x32_bf16(pa0.v, va2, acc2, 0, 0, 0);
        acc0 = __builtin_amdgcn_mfma_f32_16x16x32_bf16(pa1.v, v10, acc0, 0, 0, 0);
        acc1 = __builtin_amdgcn_mfma_f32_16x16x32_bf16(pa1.v, v11, acc1, 0, 0, 0);
        acc2 = __builtin_amdgcn_mfma_f32_16x16x32_bf16(pa1.v, va2, acc2, 0, 0, 0);
        __builtin_amdgcn_s_setprio(0);
    };

    // prologue: stage tiles 0,1 into bufs 0,1; preload tiles 2,3 into regs
    {
        bf16x8 k0t = *(const bf16x8*)(kg);
        bf16x8 v0t = *(const bf16x8*)(vg);
        bf16x8 k1t = *(const bf16x8*)(kg + 2048);
        bf16x8 v1t = *(const bf16x8*)(vg + 64);
        *(bf16x8*)(klp) = k0t;
        *(bf16x8*)(vlp) = v0t;
        *(bf16x8*)(klp + KLB) = k1t;
        *(bf16x8*)(vlp + VLB) = v1t;
    }
    __syncthreads();
    bf16x8 kA = *(const bf16x8*)(kg + 2 * 2048);
    bf16x8 vA = *(const bf16x8*)(vg + 2 * 64);
    bf16x8 kB = *(const bf16x8*)(kg + 3 * 2048);
    bf16x8 vB = *(const bf16x8*)(vg + 3 * 64);

    // steady state per ip (4 tiles, 2 barriers):
    //  half1: write bufs 2,3 <- regs (tiles 4ip+2,3); reload regs (4ip+4,5); C0; C1; bar
    //  half2: write bufs 0,1 <- regs (tiles 4ip+4,5); reload regs (4ip+6,7); C2; C3; bar
#pragma unroll 1
    for (int ip = 0; ip < 16; ++ip) {
        // ---- half 1
        *(bf16x8*)(klp + 2 * KLB) = kA;
        *(bf16x8*)(vlp + 2 * VLB) = vA;
        *(bf16x8*)(klp + 3 * KLB) = kB;
        *(bf16x8*)(vlp + 3 * VLB) = vB;
        if (ip < 15) {
            kA = *(const bf16x8*)(kg + (size_t)(4 * ip + 4) * 2048);
            vA = *(const bf16x8*)(vg + (4 * ip + 4) * 64);
            kB = *(const bf16x8*)(kg + (size_t)(4 * ip + 5) * 2048);
            vB = *(const bf16x8*)(vg + (4 * ip + 5) * 64);
        }
        COMPUTE(0);
        COMPUTE(1);
        __syncthreads();
        // ---- half 2
        if (ip < 15) {
            *(bf16x8*)(klp) = kA;
            *(bf16x8*)(vlp) = vA;
            *(bf16x8*)(klp + KLB) = kB;
            *(bf16x8*)(vlp + VLB) = vB;
            kA = *(const bf16x8*)(kg + (size_t)(4 * ip + 6) * 2048);
            vA = *(const bf16x8*)(vg + (4 * ip + 6) * 64);
            kB = *(const bf16x8*)(kg + (size_t)(4 * ip + 7) * 2048);
            vB = *(const bf16x8*)(vg + (4 * ip + 7) * 64);
        }
        COMPUTE(2);
        COMPUTE(3);
        __syncthreads();
    }

    // epilogue: l[q-row lhi*4+r] lives in acc2[r] of lane lhi*16 (col 0)
#pragma unroll
    for (int r = 0; r < 4; ++r) {
        float ls = __shfl(acc2[r], lhi * 16);
        float li = 1.f / ls;
        int row = q0 + lhi * 4 + r;
        size_t orow = ((size_t)(b * NSEQ) + row) * 256 + h * DHD;
        attn_out[orow + llo] = f2bf(acc0[r] * li);
        attn_out[orow + 16 + llo] = f2bf(acc1[r] * li);
    }
}

// ---------------- proj GEMM: LDS-staged tiles (r11, passed) ----------------
__global__ __launch_bounds__(256) void k_proj(const ushort* __restrict__ aout,
                                              const ushort* __restrict__ wt,
                                              const float* __restrict__ bias,
                                              float* __restrict__ out) {
    __shared__ __align__(16) ushort Al[64][264];
    __shared__ __align__(16) ushort Bl[64][264];
    int t = threadIdx.x;
    int w = t >> 6, lane = t & 63;
    int lhi = lane >> 4, llo = lane & 15;
    int row0 = blockIdx.x * 64;
    int n0 = blockIdx.y * 64;

#pragma unroll
    for (int j = 0; j < 8; ++j) {
        int f = j * 256 + t;
        int r = f >> 5, c = (f & 31) * 8;
        *(bf16x8*)&Al[r][c] = *(const bf16x8*)(aout + (size_t)(row0 + r) * 256 + c);
        *(bf16x8*)&Bl[r][c] = *(const bf16x8*)(wt + (size_t)(n0 + r) * 256 + c);
    }
    __syncthreads();

    f32x4 acc[4] = {};
#pragma unroll
    for (int ks = 0; ks < 8; ++ks) {
        int k0 = ks * 32 + lhi * 8;
        bf16x8 a = *(const bf16x8*)&Al[w * 16 + llo][k0];
#pragma unroll
        for (int fn = 0; fn < 4; ++fn) {
            bf16x8 b = *(const bf16x8*)&Bl[fn * 16 + llo][k0];
            acc[fn] = __builtin_amdgcn_mfma_f32_16x16x32_bf16(a, b, acc[fn], 0, 0, 0);
        }
    }
#pragma unroll
    for (int fn = 0; fn < 4; ++fn) {
        int cg = n0 + fn * 16 + llo;
        float bv = bias[cg];
#pragma unroll
        for (int r = 0; r < 4; ++r) {
            int row = row0 + w * 16 + lhi * 4 + r;
            out[(size_t)row * 256 + cg] = acc[fn][r] + bv;
        }
    }
}

extern "C" void kernel_launch(void* const* d_in, const int* in_sizes, int n_in,
                              void* d_out, int out_size, void* d_ws, size_t ws_size,
                              hipStream_t stream) {
    const float* x     = (const float*)d_in[0];
    const float* Wqkv  = (const float*)d_in[1];
    const float* bqkv  = (const float*)d_in[2];
    const float* Wproj = (const float*)d_in[3];
    const float* bproj = (const float*)d_in[4];
    float* out = (float*)d_out;

    char* ws = (char*)d_ws;
    ushort* xb     = (ushort*)(ws);                 // 8192*256*2   = 4,194,304
    ushort* wqkvT  = (ushort*)(ws + 4194304);       // 768*256*2    =   393,216
    ushort* wprojT = (ushort*)(ws + 4587520);       // 256*256*2    =   131,072
    ushort* qhb    = (ushort*)(ws + 4718592);       // 16*4096*32*2 = 4,194,304
    ushort* khb    = (ushort*)(ws + 8912896);       // 16*4096*32*2 = 4,194,304
    ushort* vT     = (ushort*)(ws + 13107200);      // 16*32*4096*2 = 4,194,304
    ushort* aoutb  = (ushort*)(ws + 17301504);      // 8192*256*2   = 4,194,304
    // total ws use: 21,495,808 bytes (proven-safe size)

    k_prep<<<2304, 256, 0, stream>>>(x, xb, Wqkv, Wproj, wqkvT, wprojT);
    k_qkv<<<dim3(128, 12), 256, 0, stream>>>(xb, wqkvT, bqkv, qhb, khb, vT);
    k_attn<<<1024, 256, 0, stream>>>(qhb, khb, vT, aoutb);
    k_proj<<<dim3(128, 4), 256, 0, stream>>>(aoutb, wprojT, bproj, out);
}